// Round 2
// baseline (9.701 us; speedup 1.0000x reference)
//
#include <hip/hip_runtime.h>
#include <math.h>

// out[b,x,y,i] = arccos(clip(sum_c cos(pi*in[b,x,y,c]), -1+EPS, 1-EPS)) / pi
// B=16, H=W=14, C=3, nx=ny=12, 4 identical output channels.
// Derivation: Z_0 commutes with every gate (qubit 0 is only a control),
// so <Z_0> = cos(pi * a_0) where a_0 = inputs[b,x,y,c] (patch corner);
// the kernel exponents p never affect the observable.

#define B_ 16
#define H_ 14
#define NX 12
#define EPS_ 1e-5f
#define PI_F 3.14159265358979323846f

__global__ void qconv_analytic(const float* __restrict__ in, float* __restrict__ out) {
    int t = blockIdx.x * blockDim.x + threadIdx.x;           // t in [0, B*NX*NX)
    const int total = B_ * NX * NX;
    if (t >= total) return;
    int y = t % NX;
    int x = (t / NX) % NX;
    int b = t / (NX * NX);

    const float* p = in + ((b * H_ + x) * H_ + y) * 3;
    float s = cosf(PI_F * p[0]) + cosf(PI_F * p[1]) + cosf(PI_F * p[2]);
    s = fminf(fmaxf(s, -1.0f + EPS_), 1.0f - EPS_);
    float v = acosf(s) * (1.0f / PI_F);

    float4 o = make_float4(v, v, v, v);
    reinterpret_cast<float4*>(out)[t] = o;                   // out[t*4 .. t*4+3]
}

extern "C" void kernel_launch(void* const* d_in, const int* in_sizes, int n_in,
                              void* d_out, int out_size, void* d_ws, size_t ws_size,
                              hipStream_t stream) {
    const float* in = (const float*)d_in[0];
    float* out = (float*)d_out;
    const int total = B_ * NX * NX;                          // 2304
    dim3 block(256);
    dim3 grid((total + 255) / 256);
    qconv_analytic<<<grid, block, 0, stream>>>(in, out);
}